// Round 5
// baseline (644.094 us; speedup 1.0000x reference)
//
#include <hip/hip_runtime.h>
#include <math.h>

// SoftMoE fp32 pipeline for MI355X.
// B=8 T=4096 D=1024 F=4096 E=8 S=4, N=E*S=32, BT=32768.
#define CB 8
#define CT 4096
#define CD 1024
#define CF 4096
#define CN 32

#define FMA4(a, s, v) { (a).x += (s)*(v).x; (a).y += (s)*(v).y; (a).z += (s)*(v).z; (a).w += (s)*(v).w; }

__device__ __forceinline__ float gelu_exact(float v){
  return 0.5f*v*(1.0f + erff(v*0.7071067811865476f));
}

// ---- workspace layout (floats) ----
// logits  [BT][32]                     @ 0         (1,048,576)
// partial [256 slabs][32][1024]        @ 1,048,576 (8,388,608)   slab = (b*32+th)
// slot_in [B][32][D]                   @ 9,437,184 (262,144)
// slot_out[B][32][D]                   @ 9,699,328 (262,144)
// h       [E][32][F]                   @ 9,961,472 (1,048,576)  row r = b*4+s
// pM/pS   [64][32] each                @ 11,010,048 / 11,012,096
// gmax/grcp [256] each                 @ 11,014,144 / 11,014,400
// total 11,014,656 floats = 44,058,624 bytes
#define OFF_LOGITS  0
#define OFF_PARTIAL 1048576
#define OFF_SLOTIN  9437184
#define OFF_SLOTOUT 9699328
#define OFF_H       9961472
#define OFF_PM      11010048
#define OFF_PS      11012096
#define OFF_GMAX    11014144
#define OFF_GRCP    11014400

// ---------------- init: slot_out = b2 broadcast ----------------
__global__ void k_init(float* __restrict__ slot_out, const float* __restrict__ b2){
  int i = blockIdx.x*256 + threadIdx.x;        // 262144 total
  int n = (i>>10)&31, d = i&1023, e = n>>2;
  slot_out[i] = b2[e*CD + d];
}

// ---------------- K1: logits[bt][n] = x[bt][:] . slots[n][:] ----------------
// grid 256 (128 rows each), block 256. Thread tile 4r x 4n.
__global__ __launch_bounds__(256) void k_logits(const float* __restrict__ x,
                                                const float* __restrict__ slots,
                                                float* __restrict__ logits){
  __shared__ float xs[32*132];   // [d][r], pad 132 keeps b128 align + spreads banks
  __shared__ float ss[32*36];    // [d][n]
  const int tid = threadIdx.x;
  const int r0 = blockIdx.x*128;
  const int nl = tid & 7, rg = tid >> 3;
  const float4* x4  = (const float4*)x;
  const float4* s4g = (const float4*)slots;
  const float4* xs4 = (const float4*)xs;
  const float4* ss4 = (const float4*)ss;
  float4 acc[4];
  acc[0]=acc[1]=acc[2]=acc[3]=make_float4(0.f,0.f,0.f,0.f);
  float4 xr[4], sr;
  #pragma unroll
  for (int it=0; it<4; ++it){ int idx = it*256+tid, r = idx>>3, c4 = idx&7;
    xr[it] = x4[(size_t)(r0+r)*256 + c4]; }
  { int n = tid>>3, c4 = tid&7; sr = s4g[n*256 + c4]; }
  for (int dc=0; dc<32; ++dc){
    __syncthreads();
    #pragma unroll
    for (int it=0; it<4; ++it){ int idx = it*256+tid, r = idx>>3, c4 = idx&7;
      xs[(c4*4+0)*132+r]=xr[it].x; xs[(c4*4+1)*132+r]=xr[it].y;
      xs[(c4*4+2)*132+r]=xr[it].z; xs[(c4*4+3)*132+r]=xr[it].w; }
    { int n = tid>>3, c4 = tid&7;
      ss[(c4*4+0)*36+n]=sr.x; ss[(c4*4+1)*36+n]=sr.y;
      ss[(c4*4+2)*36+n]=sr.z; ss[(c4*4+3)*36+n]=sr.w; }
    __syncthreads();
    if (dc+1 < 32){
      #pragma unroll
      for (int it=0; it<4; ++it){ int idx = it*256+tid, r = idx>>3, c4 = idx&7;
        xr[it] = x4[(size_t)(r0+r)*256 + (dc+1)*8 + c4]; }
      { int n = tid>>3, c4 = tid&7; sr = s4g[n*256 + (dc+1)*8 + c4]; }
    }
    #pragma unroll
    for (int d=0; d<32; ++d){
      float4 a = xs4[d*33 + rg];   // rows rg*4..+3 at depth d
      float4 s = ss4[d*9  + nl];   // slots nl*4..+3 at depth d
      FMA4(acc[0], a.x, s); FMA4(acc[1], a.y, s);
      FMA4(acc[2], a.z, s); FMA4(acc[3], a.w, s);
    }
  }
  float4* l4 = (float4*)logits;
  #pragma unroll
  for (int i=0;i<4;++i) l4[(size_t)(r0 + rg*4 + i)*8 + nl] = acc[i];
}

// ---------------- K2a: per-(b,n) online max/sumexp over 512-token chunks ----------------
__global__ __launch_bounds__(1024) void k_stats(const float* __restrict__ logits,
                                                float* __restrict__ pM, float* __restrict__ pS){
  __shared__ float ms[32*33], sx[32*33];
  const int b = blockIdx.x>>3, tc = blockIdx.x&7;
  const int tid = threadIdx.x, n = tid&31, tr = tid>>5;
  float m = -3.0e38f, s = 0.f;
  for (int i=0;i<16;++i){
    int t = tc*512 + i*32 + tr;
    float l = logits[(size_t)(b*CT + t)*32 + n];
    float nm = fmaxf(m, l);
    s = s*__expf(m-nm) + __expf(l-nm);
    m = nm;
  }
  ms[tr*33+n] = m; sx[tr*33+n] = s;
  __syncthreads();
  if (tid < 32){
    float M = -3.0e38f;
    #pragma unroll
    for (int q=0;q<32;++q) M = fmaxf(M, ms[q*33+tid]);
    float sv = 0.f;
    #pragma unroll
    for (int q=0;q<32;++q) sv += sx[q*33+tid]*__expf(ms[q*33+tid]-M);
    pM[(b*8+tc)*32+tid] = M;
    pS[(b*8+tc)*32+tid] = sv;
  }
}

__global__ void k_stats2(const float* __restrict__ pM, const float* __restrict__ pS,
                         float* __restrict__ gmax, float* __restrict__ grcp){
  const int tid = threadIdx.x, b = tid>>5, n = tid&31;
  float M = -3.0e38f;
  #pragma unroll
  for (int tc=0;tc<8;++tc) M = fmaxf(M, pM[(b*8+tc)*32+n]);
  float sv = 0.f;
  #pragma unroll
  for (int tc=0;tc<8;++tc) sv += pS[(b*8+tc)*32+n]*__expf(pM[(b*8+tc)*32+n]-M);
  gmax[tid] = M;
  grcp[tid] = 1.0f/sv;
}

// ---------------- K2b: partial[b,th][n][d] = sum_{t in chunk} exp(l-max) * x ----------------
// grid 256 = (b, th: 128-token range). Each lane: 4 d (by wave quarter), acc[32n] in regs.
__global__ __launch_bounds__(256,1) void k_dispatch(const float* __restrict__ x,
                                                    const float* __restrict__ logits,
                                                    const float* __restrict__ gmax,
                                                    float* __restrict__ partial){
  __shared__ float wl[128*32];
  __shared__ float gm[32];
  const int bid = blockIdx.x, b = bid>>5, th = bid&31;
  const int t0 = th*128;
  const int tid = threadIdx.x, dl = tid&63, tg = tid>>6;
  if (tid < 32) gm[tid] = gmax[b*32+tid];
  __syncthreads();
  #pragma unroll
  for (int it=0; it<16; ++it){
    int idx = it*256 + tid, tl = idx>>5, n = idx&31;
    float l = logits[(size_t)(b*CT + t0 + tl)*32 + n];
    wl[idx] = __expf(l - gm[n]);
  }
  __syncthreads();
  float4 acc[32];
  #pragma unroll
  for (int n=0;n<32;++n) acc[n] = make_float4(0.f,0.f,0.f,0.f);
  const float4* x4  = (const float4*)x;
  const float4* wl4 = (const float4*)wl;
  const int xcol = tg*64 + dl;   // float4 column 0..255 (all D covered by 4 waves)
  const size_t xbase = (size_t)(b*CT + t0)*256 + xcol;
  // depth-4 named prefetch rotation
  float4 xa = x4[xbase + 0*256];
  float4 xb = x4[xbase + 1*256];
  float4 xcv= x4[xbase + 2*256];
  float4 xd = x4[xbase + 3*256];
  for (int tl=0; tl<128; ++tl){
    float4 xnext;
    if (tl+4 < 128) xnext = x4[xbase + (size_t)(tl+4)*256]; else xnext = make_float4(0,0,0,0);
    #pragma unroll
    for (int k=0;k<8;++k){
      float4 w = wl4[tl*8 + k];
      FMA4(acc[4*k+0], w.x, xa);
      FMA4(acc[4*k+1], w.y, xa);
      FMA4(acc[4*k+2], w.z, xa);
      FMA4(acc[4*k+3], w.w, xa);
    }
    xa = xb; xb = xcv; xcv = xd; xd = xnext;
  }
  float4* p4 = (float4*)partial;
  #pragma unroll
  for (int n=0;n<32;++n) p4[(size_t)bid*8192 + n*256 + xcol] = acc[n];
}

// ---------------- K2c: slot_in = (sum over 32 partials) * rcp ----------------
__global__ void k_reduce(const float* __restrict__ partial, const float* __restrict__ grcp,
                         float* __restrict__ slot_in){
  const int b = blockIdx.x>>5, n = blockIdx.x&31;
  const int tid = threadIdx.x;  // float4 col 0..255
  const float4* p4 = (const float4*)partial;
  float4 v = make_float4(0.f,0.f,0.f,0.f);
  #pragma unroll
  for (int th=0; th<32; ++th){
    float4 a = p4[(size_t)(b*32+th)*8192 + n*256 + tid];
    v.x += a.x; v.y += a.y; v.z += a.z; v.w += a.w;
  }
  float r = grcp[b*32+n];
  v.x*=r; v.y*=r; v.z*=r; v.w*=r;
  ((float4*)slot_in)[(size_t)(b*32+n)*256 + tid] = v;
}

// ---------------- K3: h[e][r][f] = gelu(slot_in_row . w1[e][:,f] + b1) ----------------
// grid 256 = (e, fc:128-col chunk), block 256, thread tile 4r x 4f, K-chunk 64.
__global__ __launch_bounds__(256) void k_ffn1(const float* __restrict__ slot_in,
                                              const float* __restrict__ w1,
                                              const float* __restrict__ b1,
                                              float* __restrict__ h){
  __shared__ float At[64*36];     // [d][r] padded
  __shared__ float Wl[64*128];    // [d][f]
  const int e = blockIdx.x>>5, fc = blockIdx.x&31;
  const int tid = threadIdx.x, fl = tid&31, rg = tid>>5;
  const float4* si4 = (const float4*)slot_in;
  const float4* w14 = (const float4*)w1;
  const float4* At4 = (const float4*)At;
  const float4* Wl4 = (const float4*)Wl;
  float4 acc[4];
  acc[0]=acc[1]=acc[2]=acc[3]=make_float4(0.f,0.f,0.f,0.f);
  float4 ar[2], wr[8];
  #pragma unroll
  for (int it=0; it<2; ++it){ int idx = it*256+tid, r = idx>>4, c4 = idx&15;
    ar[it] = si4[(size_t)((r>>2)*32 + e*4 + (r&3))*256 + c4]; }
  #pragma unroll
  for (int it=0; it<8; ++it){ int idx = it*256+tid, row = idx>>5, c4 = idx&31;
    wr[it] = w14[(size_t)(e*1024 + row)*1024 + fc*32 + c4]; }
  for (int kk=0; kk<16; ++kk){
    __syncthreads();
    #pragma unroll
    for (int it=0; it<2; ++it){ int idx = it*256+tid, r = idx>>4, c4 = idx&15;
      At[(c4*4+0)*36+r]=ar[it].x; At[(c4*4+1)*36+r]=ar[it].y;
      At[(c4*4+2)*36+r]=ar[it].z; At[(c4*4+3)*36+r]=ar[it].w; }
    #pragma unroll
    for (int it=0; it<8; ++it){ int idx = it*256+tid, row = idx>>5, c4 = idx&31;
      ((float4*)Wl)[row*32 + c4] = wr[it]; }
    __syncthreads();
    if (kk+1 < 16){
      #pragma unroll
      for (int it=0; it<2; ++it){ int idx = it*256+tid, r = idx>>4, c4 = idx&15;
        ar[it] = si4[(size_t)((r>>2)*32 + e*4 + (r&3))*256 + (kk+1)*16 + c4]; }
      #pragma unroll
      for (int it=0; it<8; ++it){ int idx = it*256+tid, row = idx>>5, c4 = idx&31;
        wr[it] = w14[(size_t)(e*1024 + (kk+1)*64 + row)*1024 + fc*32 + c4]; }
    }
    #pragma unroll
    for (int dd=0; dd<64; ++dd){
      float4 a = At4[dd*9 + rg];
      float4 w = Wl4[dd*32 + fl];
      FMA4(acc[0], a.x, w); FMA4(acc[1], a.y, w);
      FMA4(acc[2], a.z, w); FMA4(acc[3], a.w, w);
    }
  }
  float4 bv = ((const float4*)b1)[e*1024 + fc*32 + fl];
  float4* h4 = (float4*)h;
  #pragma unroll
  for (int i=0;i<4;++i){
    float4 v = acc[i];
    v.x = gelu_exact(v.x + bv.x); v.y = gelu_exact(v.y + bv.y);
    v.z = gelu_exact(v.z + bv.z); v.w = gelu_exact(v.w + bv.w);
    h4[(size_t)(e*32 + rg*4 + i)*1024 + fc*32 + fl] = v;
  }
}

// ---------------- K4: slot_out += h . w2[e]  (F split 4-way, atomic) ----------------
// grid 256 = (e, dc:128-col chunk, fs:1024-F split), block 256, tile 4r x 4d.
__global__ __launch_bounds__(256) void k_ffn2(const float* __restrict__ h,
                                              const float* __restrict__ w2,
                                              float* __restrict__ slot_out){
  __shared__ float Ht[64*36];
  __shared__ float Wl[64*128];
  const int e = blockIdx.x>>5, rem = blockIdx.x&31;
  const int dc = rem>>2, fs = rem&3;
  const int tid = threadIdx.x, dl = tid&31, rg = tid>>5;
  const float4* h4  = (const float4*)h;
  const float4* w24 = (const float4*)w2;
  const float4* Ht4 = (const float4*)Ht;
  const float4* Wl4 = (const float4*)Wl;
  float4 acc[4];
  acc[0]=acc[1]=acc[2]=acc[3]=make_float4(0.f,0.f,0.f,0.f);
  float4 hr[2], wr[8];
  #pragma unroll
  for (int it=0; it<2; ++it){ int idx = it*256+tid, r = idx>>4, c4 = idx&15;
    hr[it] = h4[(size_t)(e*32+r)*1024 + fs*256 + c4]; }
  #pragma unroll
  for (int it=0; it<8; ++it){ int idx = it*256+tid, row = idx>>5, c4 = idx&31;
    wr[it] = w24[(size_t)(e*4096 + fs*1024 + row)*256 + dc*32 + c4]; }
  for (int kk=0; kk<16; ++kk){
    __syncthreads();
    #pragma unroll
    for (int it=0; it<2; ++it){ int idx = it*256+tid, r = idx>>4, c4 = idx&15;
      Ht[(c4*4+0)*36+r]=hr[it].x; Ht[(c4*4+1)*36+r]=hr[it].y;
      Ht[(c4*4+2)*36+r]=hr[it].z; Ht[(c4*4+3)*36+r]=hr[it].w; }
    #pragma unroll
    for (int it=0; it<8; ++it){ int idx = it*256+tid, row = idx>>5, c4 = idx&31;
      ((float4*)Wl)[row*32 + c4] = wr[it]; }
    __syncthreads();
    if (kk+1 < 16){
      #pragma unroll
      for (int it=0; it<2; ++it){ int idx = it*256+tid, r = idx>>4, c4 = idx&15;
        hr[it] = h4[(size_t)(e*32+r)*1024 + fs*256 + (kk+1)*16 + c4]; }
      #pragma unroll
      for (int it=0; it<8; ++it){ int idx = it*256+tid, row = idx>>5, c4 = idx&31;
        wr[it] = w24[(size_t)(e*4096 + fs*1024 + (kk+1)*64 + row)*256 + dc*32 + c4]; }
    }
    #pragma unroll
    for (int ff=0; ff<64; ++ff){
      float4 a = Ht4[ff*9 + rg];
      float4 w = Wl4[ff*32 + dl];
      FMA4(acc[0], a.x, w); FMA4(acc[1], a.y, w);
      FMA4(acc[2], a.z, w); FMA4(acc[3], a.w, w);
    }
  }
  #pragma unroll
  for (int i=0;i<4;++i){
    int r = rg*4+i;
    size_t base = (size_t)((r>>2)*32 + e*4 + (r&3))*1024 + dc*128 + dl*4;
    atomicAdd(&slot_out[base+0], acc[i].x);
    atomicAdd(&slot_out[base+1], acc[i].y);
    atomicAdd(&slot_out[base+2], acc[i].z);
    atomicAdd(&slot_out[base+3], acc[i].w);
  }
}

// ---------------- K5: out[b][t][:] = sum_n softmax_n(logits[b][t][:]) * slot_out[b][n][:] ----------------
// grid 256 = (b, tc:128 tokens). slot_out[b] tile lives in registers (32 x float4 per lane).
__global__ __launch_bounds__(256,1) void k_combine(const float* __restrict__ logits,
                                                   const float* __restrict__ slot_out,
                                                   float* __restrict__ out){
  __shared__ float wl[128*32];
  const int b = blockIdx.x>>5, tc = blockIdx.x&31;
  const int t0 = tc*128;
  const int tid = threadIdx.x;
  if (tid < 128){
    int t = t0 + tid;
    const float4* l4 = (const float4*)logits;
    float4 lv[8];
    #pragma unroll
    for (int k=0;k<8;++k) lv[k] = l4[(size_t)(b*CT + t)*8 + k];
    float m = -3.0e38f;
    #pragma unroll
    for (int k=0;k<8;++k) m = fmaxf(m, fmaxf(fmaxf(lv[k].x, lv[k].y), fmaxf(lv[k].z, lv[k].w)));
    float ex[32]; float s = 0.f;
    #pragma unroll
    for (int k=0;k<8;++k){
      ex[4*k+0] = __expf(lv[k].x-m); ex[4*k+1] = __expf(lv[k].y-m);
      ex[4*k+2] = __expf(lv[k].z-m); ex[4*k+3] = __expf(lv[k].w-m);
      s += ex[4*k+0]+ex[4*k+1]+ex[4*k+2]+ex[4*k+3];
    }
    float inv = 1.0f/s;
    #pragma unroll
    for (int n=0;n<32;++n) wl[tid*32+n] = ex[n]*inv;
  }
  const int wd = tid>>6, l = tid&63;
  const int col = wd*64 + l;  // float4 col 0..255
  const float4* so4 = (const float4*)slot_out;
  float4 sr[32];
  #pragma unroll
  for (int n=0;n<32;++n) sr[n] = so4[(size_t)(b*32+n)*256 + col];
  __syncthreads();
  const float4* wl4 = (const float4*)wl;
  float4* o4 = (float4*)out;
  for (int t=0; t<128; ++t){
    float4 acc = make_float4(0.f,0.f,0.f,0.f);
    #pragma unroll
    for (int k=0;k<8;++k){
      float4 w = wl4[t*8+k];
      FMA4(acc, w.x, sr[4*k+0]); FMA4(acc, w.y, sr[4*k+1]);
      FMA4(acc, w.z, sr[4*k+2]); FMA4(acc, w.w, sr[4*k+3]);
    }
    o4[(size_t)(b*CT + t0 + t)*256 + col] = acc;
  }
}

extern "C" void kernel_launch(void* const* d_in, const int* in_sizes, int n_in,
                              void* d_out, int out_size, void* d_ws, size_t ws_size,
                              hipStream_t stream) {
  const float* x     = (const float*)d_in[0];
  const float* slots = (const float*)d_in[1];
  const float* w1    = (const float*)d_in[2];
  const float* b1    = (const float*)d_in[3];
  const float* w2    = (const float*)d_in[4];
  const float* b2    = (const float*)d_in[5];
  float* out = (float*)d_out;
  float* ws  = (float*)d_ws;   // needs >= 44,058,624 bytes

  float* logits   = ws + OFF_LOGITS;
  float* partial  = ws + OFF_PARTIAL;
  float* slot_in  = ws + OFF_SLOTIN;
  float* slot_out = ws + OFF_SLOTOUT;
  float* h        = ws + OFF_H;
  float* pM       = ws + OFF_PM;
  float* pS       = ws + OFF_PS;
  float* gmax     = ws + OFF_GMAX;
  float* grcp     = ws + OFF_GRCP;

  k_init    <<<1024, 256, 0, stream>>>(slot_out, b2);
  k_logits  <<<256,  256, 0, stream>>>(x, slots, logits);
  k_stats   <<<64,  1024, 0, stream>>>(logits, pM, pS);
  k_stats2  <<<1,    256, 0, stream>>>(pM, pS, gmax, grcp);
  k_dispatch<<<256,  256, 0, stream>>>(x, logits, gmax, partial);
  k_reduce  <<<256,  256, 0, stream>>>(partial, grcp, slot_in);
  k_ffn1    <<<256,  256, 0, stream>>>(slot_in, w1, b1, h);
  k_ffn2    <<<256,  256, 0, stream>>>(h, w2, slot_out);
  k_combine <<<256,  256, 0, stream>>>(logits, slot_out, out);
}